// Round 1
// baseline (37.367 us; speedup 1.0000x reference)
//
#include <hip/hip_runtime.h>

// MIOSTONE tree-MLP, B=32, LEAVES=4096, H=32, K=8, D=4, OUT=2.
// Exploits block-diagonal masked weights: only reads nonzero blocks (~6 MB).

__device__ __forceinline__ float dot4(float4 a, float4 b, float acc) {
    acc = fmaf(a.x, b.x, acc);
    acc = fmaf(a.y, b.y, acc);
    acc = fmaf(a.z, b.z, acc);
    acc = fmaf(a.w, b.w, acc);
    return acc;
}

// Kernel A: per depth-2 subtree (j2 in 0..63) x row-group (rg in 0..3, 8 rows each).
// Computes layer 3 (8 leaf nodes, 32 out x 8 in each) and layer 2 (one node, 32 out x 256 in),
// both gated + linear branches, entirely in LDS. Writes X2/XL2 (32 x 2048) slices.
__global__ __launch_bounds__(256)
void k_subtree(const float* __restrict__ x,
               const float* __restrict__ Wm3, const float* __restrict__ bm3,
               const float* __restrict__ Wl3, const float* __restrict__ bl3,
               const float* __restrict__ Wm2, const float* __restrict__ bm2,
               const float* __restrict__ Wl2, const float* __restrict__ bl2,
               const float* __restrict__ gate_p,
               float* __restrict__ X2, float* __restrict__ XL2)
{
    const int j2  = blockIdx.x;   // depth-2 node 0..63
    const int rg  = blockIdx.y;   // row group 0..3
    const int tid = threadIdx.x;  // 0..255
    const float g = gate_p[0], gi = 1.0f - g;

    __shared__ __align__(16) float xs[8][64];    // input slice: 8 rows x 64 leaf cols
    __shared__ __align__(16) float x3[8][260];   // gated layer-3 out (pad 260: bank-safe)
    __shared__ __align__(16) float xl3[8][260];  // linear-chain layer-3 out

    // load x slice: rows rg*8..+7, cols j2*64..+63 (coalesced)
    {
        int b = tid >> 6, c = tid & 63;
        xs[b][c] = x[(rg * 8 + b) * 4096 + j2 * 64 + c];
        int idx = 256 + tid;
        b = idx >> 6; c = idx & 63;
        xs[b][c] = x[(rg * 8 + b) * 4096 + j2 * 64 + c];
    }
    __syncthreads();

    // ---- layer 3 (leaves): thread owns output column `tid` for all 8 rows ----
    {
        const int col = tid;
        const int l = col >> 5, t = col & 31;   // leaf-within-subtree, out-within-node
        const int j3 = j2 * 8 + l;              // global leaf node
        const int row = j3 * 32 + t;            // global weight row
        const float* wmr = Wm3 + (size_t)row * 4096 + j3 * 8;
        const float* wlr = Wl3 + (size_t)row * 4096 + j3 * 8;
        const float4 wma = *(const float4*)(wmr);
        const float4 wmb = *(const float4*)(wmr + 4);
        const float4 wla = *(const float4*)(wlr);
        const float4 wlb = *(const float4*)(wlr + 4);
        const float bmv = bm3[row], blv = bl3[row];
#pragma unroll
        for (int b = 0; b < 8; ++b) {
            const float4 xa = *(const float4*)(&xs[b][l * 8]);
            const float4 xb = *(const float4*)(&xs[b][l * 8 + 4]);
            float am = dot4(xa, wma, bmv); am = dot4(xb, wmb, am);
            float al = dot4(xa, wla, blv); al = dot4(xb, wlb, al);
            float h = fmaxf(am, 0.0f);
            x3[b][col]  = fmaf(g, h, gi * al);
            xl3[b][col] = al;
        }
    }
    __syncthreads();

    // ---- layer 2: node j2, thread = (t = tid>>3, b = tid&7) ----
    {
        const int t = tid >> 3, b = tid & 7;
        const int row = j2 * 32 + t;
        const float* wmr = Wm2 + (size_t)row * 16384 + j2 * 256;
        const float* wlr = Wl2 + (size_t)row * 16384 + j2 * 256;
        float am = bm2[row], al = bl2[row];
#pragma unroll 8
        for (int c = 0; c < 256; c += 4) {
            const float4 wm  = *(const float4*)(wmr + c);
            const float4 wl  = *(const float4*)(wlr + c);
            const float4 xv  = *(const float4*)(&x3[b][c]);
            const float4 xlv = *(const float4*)(&xl3[b][c]);
            am = dot4(xv, wm, am);
            al = dot4(xlv, wl, al);
        }
        float h = fmaxf(am, 0.0f);
        const int gb = rg * 8 + b;
        X2 [gb * 2048 + j2 * 32 + t] = fmaf(g, h, gi * al);
        XL2[gb * 2048 + j2 * 32 + t] = al;
    }
}

// Kernel B: layer 1. 8 nodes x 4 row-groups. Same structure as layer 2.
__global__ __launch_bounds__(256)
void k_layer1(const float* __restrict__ X2, const float* __restrict__ XL2,
              const float* __restrict__ Wm1, const float* __restrict__ bm1,
              const float* __restrict__ Wl1, const float* __restrict__ bl1,
              const float* __restrict__ gate_p,
              float* __restrict__ X1, float* __restrict__ XL1)
{
    const int j1  = blockIdx.x;   // 0..7
    const int rg  = blockIdx.y;   // 0..3
    const int tid = threadIdx.x;  // 0..255
    const float g = gate_p[0], gi = 1.0f - g;

    __shared__ __align__(16) float u [8][260];
    __shared__ __align__(16) float ul[8][260];
#pragma unroll
    for (int b = 0; b < 8; ++b) {
        u [b][tid] = X2 [(rg * 8 + b) * 2048 + j1 * 256 + tid];
        ul[b][tid] = XL2[(rg * 8 + b) * 2048 + j1 * 256 + tid];
    }
    __syncthreads();

    const int t = tid >> 3, b = tid & 7;
    const int row = j1 * 32 + t;
    const float* wmr = Wm1 + row * 2048 + j1 * 256;
    const float* wlr = Wl1 + row * 2048 + j1 * 256;
    float am = bm1[row], al = bl1[row];
#pragma unroll 8
    for (int c = 0; c < 256; c += 4) {
        am = dot4(*(const float4*)(&u [b][c]), *(const float4*)(wmr + c), am);
        al = dot4(*(const float4*)(&ul[b][c]), *(const float4*)(wlr + c), al);
    }
    float h = fmaxf(am, 0.0f);
    const int gb = rg * 8 + b;
    X1 [gb * 256 + row] = fmaf(g, h, gi * al);
    XL1[gb * 256 + row] = al;
}

// Kernel C: layer 0 (dense 32x256) + BatchNorm (training, biased var) + output matmul.
// Single workgroup (needs all 32 rows for BN).
__global__ __launch_bounds__(1024)
void k_tail(const float* __restrict__ X1, const float* __restrict__ XL1,
            const float* __restrict__ Wm0, const float* __restrict__ bm0,
            const float* __restrict__ Wl0, const float* __restrict__ bl0,
            const float* __restrict__ gate_p,
            const float* __restrict__ bn_gamma, const float* __restrict__ bn_beta,
            const float* __restrict__ Wout, const float* __restrict__ bout,
            float* __restrict__ out)
{
    const int tid = threadIdx.x;  // 0..1023
    const float g = gate_p[0], gi = 1.0f - g;

    __shared__ __align__(16) float v [32][260];
    __shared__ __align__(16) float vl[32][260];
    __shared__ float x0[32][33];
    __shared__ float bnm[32], bna[32];

#pragma unroll
    for (int i = 0; i < 8; ++i) {
        int idx = i * 1024 + tid;
        int b = idx >> 8, c = idx & 255;
        v [b][c] = X1 [b * 256 + c];
        vl[b][c] = XL1[b * 256 + c];
    }
    __syncthreads();

    // layer 0: thread = (t = tid>>5 output, b = tid&31 row)
    {
        const int t = tid >> 5, b = tid & 31;
        const float* wmr = Wm0 + t * 256;
        const float* wlr = Wl0 + t * 256;
        float am = bm0[t], al = bl0[t];
#pragma unroll 8
        for (int c = 0; c < 256; c += 4) {
            am = dot4(*(const float4*)(&v [b][c]), *(const float4*)(wmr + c), am);
            al = dot4(*(const float4*)(&vl[b][c]), *(const float4*)(wlr + c), al);
        }
        float h = fmaxf(am, 0.0f);
        x0[b][t] = fmaf(g, h, gi * al);
    }
    __syncthreads();

    // BatchNorm stats per feature (biased variance, as jnp.var)
    if (tid < 32) {
        const int t = tid;
        float s = 0.f, s2 = 0.f;
#pragma unroll
        for (int b = 0; b < 32; ++b) {
            float xv = x0[b][t];
            s += xv;
            s2 = fmaf(xv, xv, s2);
        }
        float mu  = s * (1.0f / 32.0f);
        float var = s2 * (1.0f / 32.0f) - mu * mu;
        float m = bn_gamma[t] * rsqrtf(var + 1e-5f);
        bnm[t] = m;
        bna[t] = fmaf(-mu, m, bn_beta[t]);
    }
    __syncthreads();

    // output matmul: (32,32) @ (32,2)^T + bout
    if (tid < 64) {
        const int b = tid >> 1, o = tid & 1;
        float acc = bout[o];
#pragma unroll
        for (int t = 0; t < 32; ++t) {
            float xn = fmaf(x0[b][t], bnm[t], bna[t]);
            acc = fmaf(xn, Wout[o * 32 + t], acc);
        }
        out[b * 2 + o] = acc;
    }
}

extern "C" void kernel_launch(void* const* d_in, const int* in_sizes, int n_in,
                              void* d_out, int out_size, void* d_ws, size_t ws_size,
                              hipStream_t stream)
{
    const float* x    = (const float*)d_in[0];
    const float* Wm3  = (const float*)d_in[1];
    const float* bm3  = (const float*)d_in[2];
    const float* Wl3  = (const float*)d_in[3];
    const float* bl3  = (const float*)d_in[4];
    const float* Wm2  = (const float*)d_in[5];
    const float* bm2  = (const float*)d_in[6];
    const float* Wl2  = (const float*)d_in[7];
    const float* bl2  = (const float*)d_in[8];
    const float* Wm1  = (const float*)d_in[9];
    const float* bm1  = (const float*)d_in[10];
    const float* Wl1  = (const float*)d_in[11];
    const float* bl1  = (const float*)d_in[12];
    const float* Wm0  = (const float*)d_in[13];
    const float* bm0  = (const float*)d_in[14];
    const float* Wl0  = (const float*)d_in[15];
    const float* bl0  = (const float*)d_in[16];
    const float* gate = (const float*)d_in[17];
    const float* bn_g = (const float*)d_in[18];
    const float* bn_b = (const float*)d_in[19];
    const float* Wout = (const float*)d_in[20];
    const float* bout = (const float*)d_in[21];
    float* out = (float*)d_out;

    float* ws  = (float*)d_ws;
    float* X2  = ws;             // 32*2048 = 65536 floats
    float* XL2 = ws + 65536;     // 65536
    float* X1  = ws + 131072;    // 8192
    float* XL1 = ws + 139264;    // 8192  (total 576 KB)

    hipLaunchKernelGGL(k_subtree, dim3(64, 4), dim3(256), 0, stream,
                       x, Wm3, bm3, Wl3, bl3, Wm2, bm2, Wl2, bl2, gate, X2, XL2);
    hipLaunchKernelGGL(k_layer1, dim3(8, 4), dim3(256), 0, stream,
                       X2, XL2, Wm1, bm1, Wl1, bl1, gate, X1, XL1);
    hipLaunchKernelGGL(k_tail, dim3(1), dim3(1024), 0, stream,
                       X1, XL1, Wm0, bm0, Wl0, bl0, gate, bn_g, bn_b, Wout, bout, out);
}